// Round 1
// 248.386 us; speedup vs baseline: 1.0054x; 1.0054x over previous
//
#include <hip/hip_runtime.h>

typedef __bf16 bf16;
typedef __bf16 bf16x8 __attribute__((ext_vector_type(8)));
typedef float floatx4 __attribute__((ext_vector_type(4)));

#define IN_F  1024
#define OUT_F 4096
#define M_DIM 8192   // 16*512
#define K_DIM 1024
#define N_DIM 4096

__device__ __forceinline__ unsigned short f2bf(float f) {
    unsigned int u = __float_as_uint(f);
    u += 0x7FFFu + ((u >> 16) & 1u);   // round-to-nearest-even
    return (unsigned short)(u >> 16);
}

// ---------------------------------------------------------------------------
// Kernel 1 (REWRITTEN): build effective weight W' (bf16, [OUT_F][IN_F] = B^T)
// W'[o,i] = a0*W[o,i] + sum_{bs in 2,4,8,16} (a_bs/bs) * D_bs[blk(o,i)][(o-i)%bs]
// where D_bs[blk][d] = sum_r W[ol+r][il + ((r+d) & (bs-1))].
//
// v2: factor the diagonal sums. Pass 2 computes each (block,level,diagonal)
// sum ONCE into LDS (3840 sums/strip, 64 ds_reads/thread); pass 3 is
// 5 lookups + 5 FMAs per output (80 ds_reads/thread). Replaces the previous
// 496 fully-unrolled ds_reads + 30-term chains per thread (16x redundant
// recomputation of each diagonal sum + spill-level register pressure).
// ---------------------------------------------------------------------------
__global__ __launch_bounds__(256) void build_w_kernel(
    const float* __restrict__ W, const float* __restrict__ alphas,
    unsigned short* __restrict__ Wb)
{
    __shared__ __align__(16) float Wl[16 * 256];   // 16 KB source strip
    __shared__ __align__(16) float D2[2048];       // [8 rb][128 cb][2 d]   8 KB
    __shared__ float D4[1024];                     // [4 rb][64 cb][4 d]    4 KB
    __shared__ float D8[512];                      // [2 rb][32 cb][8 d]    2 KB
    __shared__ float D16[256];                     // [16 cb][16 d]         1 KB

    const int t = threadIdx.x;
    const int rb = blockIdx.x >> 2;      // 256 row-blocks of 16 rows
    const int cb = blockIdx.x & 3;       // 4 col-blocks of 256 cols
    const int row0 = rb * 16, col0 = cb * 256;

    // --- pass 1: load strip (float4, coalesced) ---
    const float4* src = (const float4*)(W + (size_t)row0 * IN_F + col0);
    #pragma unroll
    for (int j = 0; j < 4; ++j) {
        const int idx = j * 256 + t;          // 0..1023 float4s
        const int r = idx >> 6, c4 = idx & 63;
        ((float4*)Wl)[r * 64 + c4] = src[(size_t)r * 256 + c4];
    }

    // --- softmax over 5 alphas (cheap, per-thread); fold in 1/bs ---
    float av[5];
    float mx = -1e30f;
    #pragma unroll
    for (int j = 0; j < 5; ++j) { av[j] = alphas[j]; mx = fmaxf(mx, av[j]); }
    float s = 0.f;
    #pragma unroll
    for (int j = 0; j < 5; ++j) { av[j] = __expf(av[j] - mx); s += av[j]; }
    const float inv = 1.f / s;
    #pragma unroll
    for (int j = 0; j < 5; ++j) av[j] *= inv;
    #pragma unroll
    for (int e = 1; e <= 4; ++e) av[e] *= 1.0f / (float)(1 << e);

    __syncthreads();

    // --- pass 2: per-(block,level,diagonal) sums, each computed once ---
    {   // D16: 256 sums, 1/thread (lanes hit 64 distinct cols -> 2-way max)
        const int c16 = t >> 4, d = t & 15;
        float acc = 0.f;
        #pragma unroll
        for (int r = 0; r < 16; ++r)
            acc += Wl[r * 256 + c16 * 16 + ((r + d) & 15)];
        D16[t] = acc;
    }
    #pragma unroll
    for (int it = 0; it < 2; ++it) {   // D8: 512 sums
        const int s8 = t + it * 256;
        const int d = s8 & 7, c8 = (s8 >> 3) & 31, r8 = s8 >> 8;
        float acc = 0.f;
        #pragma unroll
        for (int r = 0; r < 8; ++r)
            acc += Wl[(r8 * 8 + r) * 256 + c8 * 8 + ((r + d) & 7)];
        D8[s8] = acc;
    }
    #pragma unroll
    for (int it = 0; it < 4; ++it) {   // D4: 1024 sums
        const int s4 = t + it * 256;
        const int d = s4 & 3, c4 = (s4 >> 2) & 63, r4 = s4 >> 8;
        float acc = 0.f;
        #pragma unroll
        for (int r = 0; r < 4; ++r)
            acc += Wl[(r4 * 4 + r) * 256 + c4 * 4 + ((r + d) & 3)];
        D4[s4] = acc;
    }
    #pragma unroll
    for (int it = 0; it < 8; ++it) {   // D2: 2048 sums
        const int s2 = t + it * 256;
        const int d = s2 & 1, c2 = (s2 >> 1) & 127, r2 = s2 >> 8;
        D2[s2] = Wl[(r2 * 2) * 256 + c2 * 2 + d]
               + Wl[(r2 * 2 + 1) * 256 + c2 * 2 + ((1 + d) & 1)];
    }

    __syncthreads();

    // --- pass 3: 16 outputs/thread, 5 LDS lookups each ---
    // thread t -> row k = t>>4, cols col = jb*16 + (t&15): every read
    // instruction spreads over 16 distinct columns (same pattern the old
    // kernel used -> at worst 4-way aliasing, cheap).
    const int k = t >> 4, jj = t & 15;
    float res[16];
    #pragma unroll
    for (int jb = 0; jb < 16; ++jb) {
        const int col = jb * 16 + jj;
        const int dd = k - col;            // two's-complement & mask == mod
        res[jb] = av[0] * Wl[k * 256 + col]
                + av[1] * D2[((k >> 1) * 128 + (col >> 1)) * 2 + (dd & 1)]
                + av[2] * D4[((k >> 2) * 64  + (col >> 2)) * 4 + (dd & 3)]
                + av[3] * D8[((k >> 3) * 32  + (col >> 3)) * 8 + (dd & 7)]
                + av[4] * D16[(col >> 4) * 16 + (dd & 15)];
    }

    // --- repack through LDS (reuse D2 region, 8 KB) for uint4 stores ---
    __syncthreads();
    unsigned short* st = (unsigned short*)D2;
    #pragma unroll
    for (int jb = 0; jb < 16; ++jb)
        st[k * 256 + jb * 16 + jj] = f2bf(res[jb]);
    __syncthreads();

    const uint4* p = (const uint4*)(st + k * 256 + jj * 16);
    uint4* dst = (uint4*)(Wb + (size_t)(row0 + k) * IN_F + col0 + jj * 16);
    dst[0] = p[0];
    dst[1] = p[1];
}

// ---------------------------------------------------------------------------
// Kernel 2: x f32 -> bf16, 8 elements/thread (unchanged)
// ---------------------------------------------------------------------------
__global__ __launch_bounds__(256) void cvt_x_kernel(
    const float* __restrict__ x, uint4* __restrict__ xb)
{
    const int t = blockIdx.x * 256 + threadIdx.x;
    const float4* xv = (const float4*)x;
    const float4 v0 = xv[2 * t];
    const float4 v1 = xv[2 * t + 1];
    uint4 o;
    o.x = (unsigned)f2bf(v0.x) | ((unsigned)f2bf(v0.y) << 16);
    o.y = (unsigned)f2bf(v0.z) | ((unsigned)f2bf(v0.w) << 16);
    o.z = (unsigned)f2bf(v1.x) | ((unsigned)f2bf(v1.y) << 16);
    o.w = (unsigned)f2bf(v1.z) | ((unsigned)f2bf(v1.w) << 16);
    xb[t] = o;
}

// ---------------------------------------------------------------------------
// Kernel 3: C[M][N] = A[M][K] * B[N][K]^T + bias    (MFMA GEMM, XOR-swizzled LDS)
// 128x128 tile, BK=64, 256 threads (4 waves, 2x2 of 64x64), 16x16x32 bf16 MFMA.
// v2: + bijective XCD-aware blockIdx swizzle (grid 2048 % 8 == 0, simple form
// is bijective): each XCD gets a contiguous 256-tile chunk = 8 full bm rows
// -> A-panel reuse inside the XCD's private L2.
// ---------------------------------------------------------------------------
__global__ __launch_bounds__(256) void gemm_bt_kernel(
    const bf16* __restrict__ A, const bf16* __restrict__ B,
    const float* __restrict__ bias, float* __restrict__ C)
{
    constexpr int N = N_DIM, K = K_DIM;
    constexpr int TM = 128, TN = 128, TK = 64;
    constexpr int NBLK = (M_DIM / TM) * (N_DIM / TN);   // 2048

    __shared__ __align__(16) bf16 As[TM * TK];
    __shared__ __align__(16) bf16 Bs[TN * TK];

    const int t    = threadIdx.x;
    const int w    = t >> 6;
    const int l    = t & 63;
    const int quad = l >> 4;
    const int l16  = l & 15;
    const int x7   = l16 & 7;

    const int nb = N / TN;                 // 32
    // XCD-aware swizzle: NBLK % 8 == 0 -> bijective
    const int wgid = (blockIdx.x & 7) * (NBLK >> 3) + (blockIdx.x >> 3);
    const int bm = wgid / nb;
    const int bn = wgid % nb;

    const int wm = (w >> 1) * 64;
    const int wn = (w & 1) * 64;

    floatx4 acc[4][4] = {};

    // staging: LDS slot 'chunk' (lane-ordered, forced) holds global chunk
    // (row = chunk>>3, kc = (chunk&7) ^ (row&7))
    int crow[4], ccol[4], loff[4];
    #pragma unroll
    for (int q = 0; q < 4; ++q) {
        const int chunk = q * 256 + t;
        crow[q] = chunk >> 3;
        ccol[q] = (((chunk & 7) ^ ((chunk >> 3) & 7)) * 8);
        loff[q] = (q * 256 + (t & ~63)) * 8;   // elements; uniform per wave
    }

    const bf16* Abase = A + (size_t)bm * TM * K;
    const bf16* Bbase = B + (size_t)bn * TN * K;

    for (int kt = 0; kt < K; kt += TK) {
        #pragma unroll
        for (int q = 0; q < 4; ++q) {
            __builtin_amdgcn_global_load_lds(
                (const __attribute__((address_space(1))) void*)(Abase + (size_t)crow[q] * K + kt + ccol[q]),
                (__attribute__((address_space(3))) void*)(As + loff[q]), 16, 0, 0);
        }
        #pragma unroll
        for (int q = 0; q < 4; ++q) {
            __builtin_amdgcn_global_load_lds(
                (const __attribute__((address_space(1))) void*)(Bbase + (size_t)crow[q] * K + kt + ccol[q]),
                (__attribute__((address_space(3))) void*)(Bs + loff[q]), 16, 0, 0);
        }
        __syncthreads();

        #pragma unroll
        for (int ks = 0; ks < 2; ++ks) {
            bf16x8 af[4], bfr[4];
            const int kx = ((ks * 4 + quad) ^ x7) * 8;   // swizzled K-offset
            #pragma unroll
            for (int mt = 0; mt < 4; ++mt)
                af[mt] = *(const bf16x8*)(As + (wm + mt * 16 + l16) * TK + kx);
            #pragma unroll
            for (int nt = 0; nt < 4; ++nt)
                bfr[nt] = *(const bf16x8*)(Bs + (wn + nt * 16 + l16) * TK + kx);
            #pragma unroll
            for (int mt = 0; mt < 4; ++mt)
                #pragma unroll
                for (int nt = 0; nt < 4; ++nt)
                    acc[mt][nt] = __builtin_amdgcn_mfma_f32_16x16x32_bf16(
                        af[mt], bfr[nt], acc[mt][nt], 0, 0, 0);
        }
        __syncthreads();
    }

    // epilogue: C/D layout col = lane&15, row = quad*4 + reg  (m89-verified)
    float bv[4];
    #pragma unroll
    for (int nt = 0; nt < 4; ++nt)
        bv[nt] = bias[bn * TN + wn + nt * 16 + l16];

    float* Cbase = C + (size_t)(bm * TM + wm) * N + bn * TN + wn;
    #pragma unroll
    for (int mt = 0; mt < 4; ++mt) {
        #pragma unroll
        for (int r = 0; r < 4; ++r) {
            float* crowp = Cbase + (size_t)(mt * 16 + quad * 4 + r) * N;
            #pragma unroll
            for (int nt = 0; nt < 4; ++nt)
                crowp[nt * 16 + l16] = acc[mt][nt][r] + bv[nt];
        }
    }
}

// ---------------------------------------------------------------------------
extern "C" void kernel_launch(void* const* d_in, const int* in_sizes, int n_in,
                              void* d_out, int out_size, void* d_ws, size_t ws_size,
                              hipStream_t stream) {
    const float* x      = (const float*)d_in[0];   // [16,512,1024]
    const float* weight = (const float*)d_in[1];   // [4096,1024]
    const float* alphas = (const float*)d_in[2];   // [5]
    const float* bias   = (const float*)d_in[3];   // [4096]
    float* out = (float*)d_out;                    // [16,512,4096] f32

    // workspace: Wb (bf16, 8 MB) | Xb (bf16, 16 MB)
    unsigned short* Wb = (unsigned short*)d_ws;
    unsigned short* Xb = (unsigned short*)((char*)d_ws + (size_t)OUT_F * IN_F * 2);

    build_w_kernel<<<(OUT_F / 16) * (IN_F / 256), 256, 0, stream>>>(weight, alphas, Wb);
    cvt_x_kernel<<<(M_DIM * K_DIM / 8) / 256, 256, 0, stream>>>(x, (uint4*)Xb);

    const int grid = (M_DIM / 128) * (N_DIM / 128);   // 64*32 = 2048 blocks
    gemm_bt_kernel<<<grid, 256, 0, stream>>>((const bf16*)Xb, (const bf16*)Wb, bias, out);
}

// Round 2
// 237.570 us; speedup vs baseline: 1.0512x; 1.0455x over previous
//
#include <hip/hip_runtime.h>

typedef __bf16 bf16;
typedef __bf16 bf16x8 __attribute__((ext_vector_type(8)));
typedef float floatx4 __attribute__((ext_vector_type(4)));

#define IN_F  1024
#define OUT_F 4096
#define M_DIM 8192   // 16*512
#define K_DIM 1024
#define N_DIM 4096

__device__ __forceinline__ unsigned short f2bf(float f) {
    unsigned int u = __float_as_uint(f);
    u += 0x7FFFu + ((u >> 16) & 1u);   // round-to-nearest-even
    return (unsigned short)(u >> 16);
}

// ---------------------------------------------------------------------------
// Kernel 1: build effective weight W' (bf16, [OUT_F][IN_F] = B^T)
// Factored diagonal sums (see round-1 notes): pass 2 computes each
// (block,level,diagonal) sum once into LDS; pass 3 is 5 lookups + 5 FMAs.
// ---------------------------------------------------------------------------
__global__ __launch_bounds__(256) void build_w_kernel(
    const float* __restrict__ W, const float* __restrict__ alphas,
    unsigned short* __restrict__ Wb)
{
    __shared__ __align__(16) float Wl[16 * 256];   // 16 KB source strip
    __shared__ __align__(16) float D2[2048];       // [8 rb][128 cb][2 d]   8 KB
    __shared__ float D4[1024];                     // [4 rb][64 cb][4 d]    4 KB
    __shared__ float D8[512];                      // [2 rb][32 cb][8 d]    2 KB
    __shared__ float D16[256];                     // [16 cb][16 d]         1 KB

    const int t = threadIdx.x;
    const int rb = blockIdx.x >> 2;      // 256 row-blocks of 16 rows
    const int cb = blockIdx.x & 3;       // 4 col-blocks of 256 cols
    const int row0 = rb * 16, col0 = cb * 256;

    // --- pass 1: load strip (float4, coalesced) ---
    const float4* src = (const float4*)(W + (size_t)row0 * IN_F + col0);
    #pragma unroll
    for (int j = 0; j < 4; ++j) {
        const int idx = j * 256 + t;          // 0..1023 float4s
        const int r = idx >> 6, c4 = idx & 63;
        ((float4*)Wl)[r * 64 + c4] = src[(size_t)r * 256 + c4];
    }

    // --- softmax over 5 alphas (cheap, per-thread); fold in 1/bs ---
    float av[5];
    float mx = -1e30f;
    #pragma unroll
    for (int j = 0; j < 5; ++j) { av[j] = alphas[j]; mx = fmaxf(mx, av[j]); }
    float s = 0.f;
    #pragma unroll
    for (int j = 0; j < 5; ++j) { av[j] = __expf(av[j] - mx); s += av[j]; }
    const float inv = 1.f / s;
    #pragma unroll
    for (int j = 0; j < 5; ++j) av[j] *= inv;
    #pragma unroll
    for (int e = 1; e <= 4; ++e) av[e] *= 1.0f / (float)(1 << e);

    __syncthreads();

    // --- pass 2: per-(block,level,diagonal) sums, each computed once ---
    {   // D16: 256 sums, 1/thread
        const int c16 = t >> 4, d = t & 15;
        float acc = 0.f;
        #pragma unroll
        for (int r = 0; r < 16; ++r)
            acc += Wl[r * 256 + c16 * 16 + ((r + d) & 15)];
        D16[t] = acc;
    }
    #pragma unroll
    for (int it = 0; it < 2; ++it) {   // D8: 512 sums
        const int s8 = t + it * 256;
        const int d = s8 & 7, c8 = (s8 >> 3) & 31, r8 = s8 >> 8;
        float acc = 0.f;
        #pragma unroll
        for (int r = 0; r < 8; ++r)
            acc += Wl[(r8 * 8 + r) * 256 + c8 * 8 + ((r + d) & 7)];
        D8[s8] = acc;
    }
    #pragma unroll
    for (int it = 0; it < 4; ++it) {   // D4: 1024 sums
        const int s4 = t + it * 256;
        const int d = s4 & 3, c4 = (s4 >> 2) & 63, r4 = s4 >> 8;
        float acc = 0.f;
        #pragma unroll
        for (int r = 0; r < 4; ++r)
            acc += Wl[(r4 * 4 + r) * 256 + c4 * 4 + ((r + d) & 3)];
        D4[s4] = acc;
    }
    #pragma unroll
    for (int it = 0; it < 8; ++it) {   // D2: 2048 sums
        const int s2 = t + it * 256;
        const int d = s2 & 1, c2 = (s2 >> 1) & 127, r2 = s2 >> 8;
        D2[s2] = Wl[(r2 * 2) * 256 + c2 * 2 + d]
               + Wl[(r2 * 2 + 1) * 256 + c2 * 2 + ((1 + d) & 1)];
    }

    __syncthreads();

    // --- pass 3: 16 outputs/thread, 5 LDS lookups each ---
    const int k = t >> 4, jj = t & 15;
    float res[16];
    #pragma unroll
    for (int jb = 0; jb < 16; ++jb) {
        const int col = jb * 16 + jj;
        const int dd = k - col;            // two's-complement & mask == mod
        res[jb] = av[0] * Wl[k * 256 + col]
                + av[1] * D2[((k >> 1) * 128 + (col >> 1)) * 2 + (dd & 1)]
                + av[2] * D4[((k >> 2) * 64  + (col >> 2)) * 4 + (dd & 3)]
                + av[3] * D8[((k >> 3) * 32  + (col >> 3)) * 8 + (dd & 7)]
                + av[4] * D16[(col >> 4) * 16 + (dd & 15)];
    }

    // --- repack through LDS (reuse D2 region) for uint4 stores ---
    __syncthreads();
    unsigned short* st = (unsigned short*)D2;
    #pragma unroll
    for (int jb = 0; jb < 16; ++jb)
        st[k * 256 + jb * 16 + jj] = f2bf(res[jb]);
    __syncthreads();

    const uint4* p = (const uint4*)(st + k * 256 + jj * 16);
    uint4* dst = (uint4*)(Wb + (size_t)(row0 + k) * IN_F + col0 + jj * 16);
    dst[0] = p[0];
    dst[1] = p[1];
}

// ---------------------------------------------------------------------------
// Kernel 2: x f32 -> bf16, 8 elements/thread (unchanged)
// ---------------------------------------------------------------------------
__global__ __launch_bounds__(256) void cvt_x_kernel(
    const float* __restrict__ x, uint4* __restrict__ xb)
{
    const int t = blockIdx.x * 256 + threadIdx.x;
    const float4* xv = (const float4*)x;
    const float4 v0 = xv[2 * t];
    const float4 v1 = xv[2 * t + 1];
    uint4 o;
    o.x = (unsigned)f2bf(v0.x) | ((unsigned)f2bf(v0.y) << 16);
    o.y = (unsigned)f2bf(v0.z) | ((unsigned)f2bf(v0.w) << 16);
    o.z = (unsigned)f2bf(v1.x) | ((unsigned)f2bf(v1.y) << 16);
    o.w = (unsigned)f2bf(v1.z) | ((unsigned)f2bf(v1.w) << 16);
    xb[t] = o;
}

// ---------------------------------------------------------------------------
// Kernel 3 (RESTRUCTURED): C[M][N] = A[M][K] * B[N][K]^T + bias
// Ring-3 deep-pipelined MFMA GEMM (T3+T4+T5 from the catalog):
//   BM=256 x BN=128 tile, BK=64, 512 threads = 8 waves (4M x 2N of 64x64).
//   LDS: 3 K-tile slots x (A 32KB + B 16KB) = 144 KB -> 1 block/CU,
//        8 waves = 2 waves/SIMD.
//   Pipeline: stage kt+2 while computing kt; K-tile boundary waits
//   s_waitcnt vmcnt(6) (= kt+1's in-flight loads) -- counted, NEVER 0 in
//   the main loop (T4); only the final K-tile drains.
//   Each K-tile = 2 phases: {8 ds_read_b128 || stage -> s_barrier ->
//   setprio(1) -> 16 MFMA -> setprio(0)} (T3+T5).
//   XOR-swizzle staging (chunk kc = (c&7) ^ (row&7)) + fragment reads carried
//   over verbatim from the verified 128^2 kernel (bank conflicts were 0).
//   Natural block order: nb=32 => XCD x owns bn in {x, x+8, x+16, x+24},
//   B-panels stay resident in its private L2 across all bm rows (round-1
//   lesson: the "contiguous chunk" swizzle streams all of B per XCD -> worse).
// ---------------------------------------------------------------------------
#define TM 256
#define TN 128
#define TK 64
#define A_SLOT_EL (TM * TK)            // 16384 bf16 = 32 KB
#define B_SLOT_EL (TN * TK)            // 8192  bf16 = 16 KB
#define SLOT_EL   (A_SLOT_EL + B_SLOT_EL)

__global__ __launch_bounds__(512, 2) void gemm_bt_kernel(
    const bf16* __restrict__ A, const bf16* __restrict__ B,
    const float* __restrict__ bias, float* __restrict__ C)
{
    constexpr int N = N_DIM, K = K_DIM;
    constexpr int NT = K / TK;             // 16 K-tiles

    __shared__ __align__(16) bf16 smem[3 * SLOT_EL];   // 144 KB

    const int t    = threadIdx.x;
    const int w    = t >> 6;               // wave 0..7
    const int l    = t & 63;
    const int quad = l >> 4;
    const int l16  = l & 15;
    const int x7   = l16 & 7;

    const int nb = N / TN;                 // 32
    const int bm = blockIdx.x / nb;
    const int bn = blockIdx.x % nb;

    const int wm = (w >> 1) * 64;          // 0,64,128,192 (A rows)
    const int wn = (w & 1) * 64;           // 0,64         (B rows)

    floatx4 acc[4][4] = {};

    // staging map: LDS chunk c (16B) holds global (row = c>>3, kc = (c&7)^(row&7))
    int crow[4], ccol[4], loff[4];
    #pragma unroll
    for (int q = 0; q < 4; ++q) {
        const int chunk = q * 512 + t;
        crow[q] = chunk >> 3;                              // 0..255
        ccol[q] = ((chunk & 7) ^ ((chunk >> 3) & 7)) * 8;  // elements
        loff[q] = (q * 512 + (t & ~63)) * 8;               // wave-uniform + lane*16B
    }

    const bf16* Abase = A + (size_t)bm * TM * K;
    const bf16* Bbase = B + (size_t)bn * TN * K;

    // ---- staging helpers (A: 4 loads/thread, B: 2 loads/thread) ----
#define STAGE_A(KT, SLOT)                                                        \
    do {                                                                         \
        _Pragma("unroll")                                                        \
        for (int q = 0; q < 4; ++q)                                              \
            __builtin_amdgcn_global_load_lds(                                    \
                (const __attribute__((address_space(1))) void*)(                 \
                    Abase + (size_t)crow[q] * K + (KT) * TK + ccol[q]),          \
                (__attribute__((address_space(3))) void*)((SLOT) + loff[q]),     \
                16, 0, 0);                                                       \
    } while (0)

#define STAGE_B(KT, SLOT)                                                        \
    do {                                                                         \
        _Pragma("unroll")                                                        \
        for (int q = 0; q < 2; ++q)                                              \
            __builtin_amdgcn_global_load_lds(                                    \
                (const __attribute__((address_space(1))) void*)(                 \
                    Bbase + (size_t)crow[q] * K + (KT) * TK + ccol[q]),          \
                (__attribute__((address_space(3))) void*)((SLOT) + A_SLOT_EL +   \
                                                          loff[q]),              \
                16, 0, 0);                                                       \
    } while (0)

    // ---- one phase: 8 ds_read_b128 || stage -> barrier -> prio(1) 16 MFMA ----
#define PHASE(SA, SB, KS, STAGE_STMT)                                            \
    do {                                                                         \
        bf16x8 af[4], bfr[4];                                                    \
        const int kx = (((KS) * 4 + quad) ^ x7) * 8;                             \
        _Pragma("unroll")                                                        \
        for (int mt = 0; mt < 4; ++mt)                                           \
            af[mt] = *(const bf16x8*)((SA) + (wm + mt * 16 + l16) * TK + kx);    \
        _Pragma("unroll")                                                        \
        for (int nt = 0; nt < 4; ++nt)                                           \
            bfr[nt] = *(const bf16x8*)((SB) + (wn + nt * 16 + l16) * TK + kx);   \
        STAGE_STMT;                                                              \
        __builtin_amdgcn_s_barrier();                                            \
        __builtin_amdgcn_s_setprio(1);                                           \
        _Pragma("unroll")                                                        \
        for (int mt = 0; mt < 4; ++mt)                                           \
            _Pragma("unroll")                                                    \
            for (int nt = 0; nt < 4; ++nt)                                       \
                acc[mt][nt] = __builtin_amdgcn_mfma_f32_16x16x32_bf16(           \
                    af[mt], bfr[nt], acc[mt][nt], 0, 0, 0);                      \
        __builtin_amdgcn_s_setprio(0);                                           \
    } while (0)

    // ---- prologue: stage kt=0 -> slot0, kt=1 -> slot1 (12 loads in flight) ----
    bf16* s0 = smem;
    bf16* s1 = smem + SLOT_EL;
    bf16* s2 = smem + 2 * SLOT_EL;
    STAGE_A(0, s0); STAGE_B(0, s0);
    STAGE_A(1, s1); STAGE_B(1, s1);

    // ---- main loop over 16 K-tiles ----
    #pragma unroll 1
    for (int kt = 0; kt < NT; ++kt) {
        // K-tile boundary: retire kt's loads (counted wait, never 0 except tail)
        if (kt == NT - 1)
            asm volatile("s_waitcnt vmcnt(0)" ::: "memory");
        else
            asm volatile("s_waitcnt vmcnt(6)" ::: "memory");
        __builtin_amdgcn_s_barrier();

        bf16* Sa = s0;
        bf16* Sb = s0 + A_SLOT_EL;
        const bool st = (kt + 2 < NT);

        PHASE(Sa, Sb, 0, if (st) STAGE_A(kt + 2, s2));
        PHASE(Sa, Sb, 1, if (st) STAGE_B(kt + 2, s2));

        // rotate ring: s0<-s1 (kt+1), s1<-s2 (kt+2), s2<-old s0 (free)
        bf16* tmp = s0; s0 = s1; s1 = s2; s2 = tmp;
    }
#undef PHASE
#undef STAGE_A
#undef STAGE_B

    // ---- epilogue: C/D layout col = lane&15, row = quad*4 + reg ----
    float bv[4];
    #pragma unroll
    for (int nt = 0; nt < 4; ++nt)
        bv[nt] = bias[bn * TN + wn + nt * 16 + l16];

    float* Cbase = C + (size_t)(bm * TM + wm) * N + bn * TN + wn;
    #pragma unroll
    for (int mt = 0; mt < 4; ++mt) {
        #pragma unroll
        for (int r = 0; r < 4; ++r) {
            float* crowp = Cbase + (size_t)(mt * 16 + quad * 4 + r) * N;
            #pragma unroll
            for (int nt = 0; nt < 4; ++nt)
                crowp[nt * 16 + l16] = acc[mt][nt][r] + bv[nt];
        }
    }
}

// ---------------------------------------------------------------------------
extern "C" void kernel_launch(void* const* d_in, const int* in_sizes, int n_in,
                              void* d_out, int out_size, void* d_ws, size_t ws_size,
                              hipStream_t stream) {
    const float* x      = (const float*)d_in[0];   // [16,512,1024]
    const float* weight = (const float*)d_in[1];   // [4096,1024]
    const float* alphas = (const float*)d_in[2];   // [5]
    const float* bias   = (const float*)d_in[3];   // [4096]
    float* out = (float*)d_out;                    // [16,512,4096] f32

    // workspace: Wb (bf16, 8 MB) | Xb (bf16, 16 MB)
    unsigned short* Wb = (unsigned short*)d_ws;
    unsigned short* Xb = (unsigned short*)((char*)d_ws + (size_t)OUT_F * IN_F * 2);

    build_w_kernel<<<(OUT_F / 16) * (IN_F / 256), 256, 0, stream>>>(weight, alphas, Wb);
    cvt_x_kernel<<<(M_DIM * K_DIM / 8) / 256, 256, 0, stream>>>(x, (uint4*)Xb);

    const int grid = (M_DIM / TM) * (N_DIM / TN);   // 32*32 = 1024 blocks
    gemm_bt_kernel<<<grid, 512, 0, stream>>>((const bf16*)Xb, (const bf16*)Wb, bias, out);
}

// Round 3
// 233.156 us; speedup vs baseline: 1.0711x; 1.0189x over previous
//
#include <hip/hip_runtime.h>

typedef __bf16 bf16;
typedef __bf16 bf16x8 __attribute__((ext_vector_type(8)));
typedef float floatx4 __attribute__((ext_vector_type(4)));

#define IN_F  1024
#define OUT_F 4096
#define M_DIM 8192   // 16*512
#define K_DIM 1024
#define N_DIM 4096

__device__ __forceinline__ unsigned short f2bf(float f) {
    unsigned int u = __float_as_uint(f);
    u += 0x7FFFu + ((u >> 16) & 1u);   // round-to-nearest-even
    return (unsigned short)(u >> 16);
}

// ---------------------------------------------------------------------------
// Kernel 1: build effective weight W' (bf16, [OUT_F][IN_F] = B^T)
// Factored diagonal sums: pass 2 computes each (block,level,diagonal) sum
// once into LDS; pass 3 is 5 lookups + 5 FMAs per output.
// ---------------------------------------------------------------------------
__global__ __launch_bounds__(256) void build_w_kernel(
    const float* __restrict__ W, const float* __restrict__ alphas,
    unsigned short* __restrict__ Wb)
{
    __shared__ __align__(16) float Wl[16 * 256];   // 16 KB source strip
    __shared__ __align__(16) float D2[2048];       // [8 rb][128 cb][2 d]   8 KB
    __shared__ float D4[1024];                     // [4 rb][64 cb][4 d]    4 KB
    __shared__ float D8[512];                      // [2 rb][32 cb][8 d]    2 KB
    __shared__ float D16[256];                     // [16 cb][16 d]         1 KB

    const int t = threadIdx.x;
    const int rb = blockIdx.x >> 2;      // 256 row-blocks of 16 rows
    const int cb = blockIdx.x & 3;       // 4 col-blocks of 256 cols
    const int row0 = rb * 16, col0 = cb * 256;

    // --- pass 1: load strip (float4, coalesced) ---
    const float4* src = (const float4*)(W + (size_t)row0 * IN_F + col0);
    #pragma unroll
    for (int j = 0; j < 4; ++j) {
        const int idx = j * 256 + t;          // 0..1023 float4s
        const int r = idx >> 6, c4 = idx & 63;
        ((float4*)Wl)[r * 64 + c4] = src[(size_t)r * 256 + c4];
    }

    // --- softmax over 5 alphas (cheap, per-thread); fold in 1/bs ---
    float av[5];
    float mx = -1e30f;
    #pragma unroll
    for (int j = 0; j < 5; ++j) { av[j] = alphas[j]; mx = fmaxf(mx, av[j]); }
    float s = 0.f;
    #pragma unroll
    for (int j = 0; j < 5; ++j) { av[j] = __expf(av[j] - mx); s += av[j]; }
    const float inv = 1.f / s;
    #pragma unroll
    for (int j = 0; j < 5; ++j) av[j] *= inv;
    #pragma unroll
    for (int e = 1; e <= 4; ++e) av[e] *= 1.0f / (float)(1 << e);

    __syncthreads();

    // --- pass 2: per-(block,level,diagonal) sums, each computed once ---
    {   // D16: 256 sums, 1/thread
        const int c16 = t >> 4, d = t & 15;
        float acc = 0.f;
        #pragma unroll
        for (int r = 0; r < 16; ++r)
            acc += Wl[r * 256 + c16 * 16 + ((r + d) & 15)];
        D16[t] = acc;
    }
    #pragma unroll
    for (int it = 0; it < 2; ++it) {   // D8: 512 sums
        const int s8 = t + it * 256;
        const int d = s8 & 7, c8 = (s8 >> 3) & 31, r8 = s8 >> 8;
        float acc = 0.f;
        #pragma unroll
        for (int r = 0; r < 8; ++r)
            acc += Wl[(r8 * 8 + r) * 256 + c8 * 8 + ((r + d) & 7)];
        D8[s8] = acc;
    }
    #pragma unroll
    for (int it = 0; it < 4; ++it) {   // D4: 1024 sums
        const int s4 = t + it * 256;
        const int d = s4 & 3, c4 = (s4 >> 2) & 63, r4 = s4 >> 8;
        float acc = 0.f;
        #pragma unroll
        for (int r = 0; r < 4; ++r)
            acc += Wl[(r4 * 4 + r) * 256 + c4 * 4 + ((r + d) & 3)];
        D4[s4] = acc;
    }
    #pragma unroll
    for (int it = 0; it < 8; ++it) {   // D2: 2048 sums
        const int s2 = t + it * 256;
        const int d = s2 & 1, c2 = (s2 >> 1) & 127, r2 = s2 >> 8;
        D2[s2] = Wl[(r2 * 2) * 256 + c2 * 2 + d]
               + Wl[(r2 * 2 + 1) * 256 + c2 * 2 + ((1 + d) & 1)];
    }

    __syncthreads();

    // --- pass 3: 16 outputs/thread, 5 LDS lookups each ---
    const int k = t >> 4, jj = t & 15;
    float res[16];
    #pragma unroll
    for (int jb = 0; jb < 16; ++jb) {
        const int col = jb * 16 + jj;
        const int dd = k - col;            // two's-complement & mask == mod
        res[jb] = av[0] * Wl[k * 256 + col]
                + av[1] * D2[((k >> 1) * 128 + (col >> 1)) * 2 + (dd & 1)]
                + av[2] * D4[((k >> 2) * 64  + (col >> 2)) * 4 + (dd & 3)]
                + av[3] * D8[((k >> 3) * 32  + (col >> 3)) * 8 + (dd & 7)]
                + av[4] * D16[(col >> 4) * 16 + (dd & 15)];
    }

    // --- repack through LDS (reuse D2 region) for uint4 stores ---
    __syncthreads();
    unsigned short* st = (unsigned short*)D2;
    #pragma unroll
    for (int jb = 0; jb < 16; ++jb)
        st[k * 256 + jb * 16 + jj] = f2bf(res[jb]);
    __syncthreads();

    const uint4* p = (const uint4*)(st + k * 256 + jj * 16);
    uint4* dst = (uint4*)(Wb + (size_t)(row0 + k) * IN_F + col0 + jj * 16);
    dst[0] = p[0];
    dst[1] = p[1];
}

// ---------------------------------------------------------------------------
// Kernel 2: x f32 -> bf16, 8 elements/thread (unchanged)
// ---------------------------------------------------------------------------
__global__ __launch_bounds__(256) void cvt_x_kernel(
    const float* __restrict__ x, uint4* __restrict__ xb)
{
    const int t = blockIdx.x * 256 + threadIdx.x;
    const float4* xv = (const float4*)x;
    const float4 v0 = xv[2 * t];
    const float4 v1 = xv[2 * t + 1];
    uint4 o;
    o.x = (unsigned)f2bf(v0.x) | ((unsigned)f2bf(v0.y) << 16);
    o.y = (unsigned)f2bf(v0.z) | ((unsigned)f2bf(v0.w) << 16);
    o.z = (unsigned)f2bf(v1.x) | ((unsigned)f2bf(v1.y) << 16);
    o.w = (unsigned)f2bf(v1.z) | ((unsigned)f2bf(v1.w) << 16);
    xb[t] = o;
}

// ---------------------------------------------------------------------------
// Kernel 3 (RESTRUCTURED v3): C = A[M][K] * B[N][K]^T + bias
// 256x256 tile, BK=64, 512 thr = 8 waves (2M x 4N), per-wave 128x64 output
// (acc[8][4]) -> FLOP per LDS-byte 42.7 vs 32 for 64x64 waves.
// 9-slot half-tile ring (LDS 144 KB): half = 256 rows x 32 K (16 KB),
// tile t = halves {4t+j}: j0=A-k0, j1=B-k0, j2=A-k1, j3=B-k1; slot = H % 9.
// 4 phases/tile: p0 {read A-k0(8) B-k0(n0,n1), stage H=4t+7, bar, 16 MFMA}
//                p1 {read B-k0(n2,n3) (A reused), stage 4t+8, bar, 16 MFMA}
//                p2/p3 same for k1, staging 4t+9 (=slot of A-k0, freed at p0)
//                and 4t+10 (=slot of B-k0, freed at p1).
// Stage lead = 7 halves (~2 tiles, >1200cyc > HBM lat). vmcnt(10) at p0/p2,
// constant through tile 13; tapers 10/8/4/0 in peeled tiles 14,15. Never a
// mid-loop drain (T4). setprio around each MFMA cluster (T5).
// Swizzle: half rows = 64B = 4 chunks; chunk s holds K-quad s ^ ((row>>1)&3);
// frag read s = quad ^ ((l16>>1)&3) -> even 8-lane/bank-quad spread
// (conflict-free); staging pre-swizzles the GLOBAL source address, LDS dest
// stays lane-linear (global_load_lds requirement).
// ---------------------------------------------------------------------------
#define TM 256
#define TN 256
#define TK 64
#define HALF_EL 8192   // 256 rows x 32 K bf16 = 16 KB
#define NSLOT 9

__global__ __launch_bounds__(512, 2) void gemm_bt_kernel(
    const bf16* __restrict__ A, const bf16* __restrict__ B,
    const float* __restrict__ bias, float* __restrict__ C)
{
    constexpr int N = N_DIM, K = K_DIM;

    __shared__ __align__(16) bf16 smem[NSLOT * HALF_EL];   // 147456 B

    const int t    = threadIdx.x;
    const int w    = t >> 6;
    const int l    = t & 63;
    const int quad = l >> 4;
    const int l16  = l & 15;

    const int wr = w >> 2;       // 0..1
    const int wc = w & 3;        // 0..3
    const int wm = wr * 128;
    const int wn = wc * 64;

    const int nb = N / TN;       // 16
    const int bm = blockIdx.x / nb;
    const int bn = blockIdx.x % nb;

    // frag-read per-lane offset within a half (elements):
    // row=l16 within group, K-chunk slot = quad ^ ((row>>1)&3)
    // ((wm+m*16+l16)>>1)&3 == (l16>>1)&3 since wm,m*16 are multiples of 8*2
    const int fko = l16 * 32 + ((quad ^ ((l16 >> 1) & 3)) * 8);

    // staging: thread handles chunks c = t and 512+t of each half.
    // chunk c -> row = c>>2, holds K-quad (c&3)^((c>>3)&3) (pre-swizzled src)
    int sloff0, sloff1;
    const bf16 *As0p, *As1p, *Bs0p, *Bs1p;
    {
        const int c0 = t, c1 = 512 + t;
        const int r0 = c0 >> 2, r1 = c1 >> 2;
        const int k0 = ((c0 & 3) ^ ((c0 >> 3) & 3)) * 8;
        const int k1 = ((c1 & 3) ^ ((c1 >> 3) & 3)) * 8;
        sloff0 = (t & ~63) * 8;          // wave-uniform LDS base (elements)
        sloff1 = (512 + (t & ~63)) * 8;
        const bf16* Abase = A + (size_t)bm * TM * K;
        const bf16* Bbase = B + (size_t)bn * TN * K;
        As0p = Abase + (size_t)r0 * K + k0;
        As1p = Abase + (size_t)r1 * K + k1;
        Bs0p = Bbase + (size_t)r0 * K + k0;
        Bs1p = Bbase + (size_t)r1 * K + k1;
    }

    floatx4 acc[8][4] = {};

#define GLL(SRC, DST)                                                         \
    __builtin_amdgcn_global_load_lds(                                         \
        (const __attribute__((address_space(1))) void*)(SRC),                 \
        (__attribute__((address_space(3))) void*)(DST), 16, 0, 0)

    // stage half (tile TT, part J): J is a compile-time literal at every use
#define STAGE(TT, J, SL) do {                                                 \
        const bf16* g0_ = ((J) & 1) ? Bs0p : As0p;                            \
        const bf16* g1_ = ((J) & 1) ? Bs1p : As1p;                            \
        const int ko_ = (TT) * TK + ((J) >> 1) * 32;                          \
        bf16* lb_ = smem + (SL) * HALF_EL;                                    \
        GLL(g0_ + ko_, lb_ + sloff0);                                         \
        GLL(g1_ + ko_, lb_ + sloff1);                                         \
    } while (0)

#define MF(d, va, vb)                                                         \
    d = __builtin_amdgcn_mfma_f32_16x16x32_bf16(va, vb, d, 0, 0, 0)

    // ---- prologue: halves 0..6 (tile0 all, tile1 j0..j2) = 14 loads ----
    STAGE(0, 0, 0); STAGE(0, 1, 1); STAGE(0, 2, 2); STAGE(0, 3, 3);
    STAGE(1, 0, 4); STAGE(1, 1, 5); STAGE(1, 2, 6);

    bf16x8 af[8], bfr[4];
    int s4 = 0;   // slot of half 4T

#define TILE_BODY(T, V0, V2, DO0, DO1, DO2, DO3) do {                         \
    const int slA0 = s4;                                                      \
    const int slB0 = s4 + 1 - ((s4 + 1 >= NSLOT) ? NSLOT : 0);                \
    const int slA1 = s4 + 2 - ((s4 + 2 >= NSLOT) ? NSLOT : 0);                \
    const int slB1 = s4 + 3 - ((s4 + 3 >= NSLOT) ? NSLOT : 0);                \
    const int sp0  = s4 + 7 - ((s4 + 7 >= NSLOT) ? NSLOT : 0);                \
    const int sp1  = s4 + 8 - ((s4 + 8 >= NSLOT) ? NSLOT : 0);                \
    /* ---- p0: needs halves 4T,4T+1 landed ---- */                           \
    asm volatile("s_waitcnt vmcnt(" V0 ")" ::: "memory");                     \
    __builtin_amdgcn_s_barrier();                                             \
    {                                                                         \
        const bf16* a0_ = smem + slA0 * HALF_EL + wm * 32 + fko;              \
        const bf16* b0_ = smem + slB0 * HALF_EL + wn * 32 + fko;              \
        _Pragma("unroll")                                                     \
        for (int m = 0; m < 8; ++m)                                           \
            af[m] = *(const bf16x8*)(a0_ + m * 512);                          \
        bfr[0] = *(const bf16x8*)(b0_);                                       \
        bfr[1] = *(const bf16x8*)(b0_ + 512);                                 \
        if (DO0) STAGE((T) + 1, 3, sp0);                                      \
        __builtin_amdgcn_s_setprio(1);                                        \
        _Pragma("unroll")                                                     \
        for (int m = 0; m < 8; ++m) {                                         \
            MF(acc[m][0], af[m], bfr[0]);                                     \
            MF(acc[m][1], af[m], bfr[1]);                                     \
        }                                                                     \
        __builtin_amdgcn_s_setprio(0);                                        \
        /* ---- p1: B-k0 n2,n3 (A reused) ---- */                             \
        __builtin_amdgcn_s_barrier();                                         \
        bfr[2] = *(const bf16x8*)(b0_ + 1024);                                \
        bfr[3] = *(const bf16x8*)(b0_ + 1536);                                \
        if (DO1) STAGE((T) + 2, 0, sp1);                                      \
        __builtin_amdgcn_s_setprio(1);                                        \
        _Pragma("unroll")                                                     \
        for (int m = 0; m < 8; ++m) {                                         \
            MF(acc[m][2], af[m], bfr[2]);                                     \
            MF(acc[m][3], af[m], bfr[3]);                                     \
        }                                                                     \
        __builtin_amdgcn_s_setprio(0);                                        \
    }                                                                         \
    /* ---- p2: needs halves 4T+2,4T+3 landed ---- */                         \
    asm volatile("s_waitcnt vmcnt(" V2 ")" ::: "memory");                     \
    __builtin_amdgcn_s_barrier();                                             \
    {                                                                         \
        const bf16* a1_ = smem + slA1 * HALF_EL + wm * 32 + fko;              \
        const bf16* b1_ = smem + slB1 * HALF_EL + wn * 32 + fko;              \
        _Pragma("unroll")                                                     \
        for (int m = 0; m < 8; ++m)                                           \
            af[m] = *(const bf16x8*)(a1_ + m * 512);                          \
        bfr[0] = *(const bf16x8*)(b1_);                                       \
        bfr[1] = *(const bf16x8*)(b1_ + 512);                                 \
        if (DO2) STAGE((T) + 2, 1, slA0);   /* slot of A-k0, freed at p0 */   \
        __builtin_amdgcn_s_setprio(1);                                        \
        _Pragma("unroll")                                                     \
        for (int m = 0; m < 8; ++m) {                                         \
            MF(acc[m][0], af[m], bfr[0]);                                     \
            MF(acc[m][1], af[m], bfr[1]);                                     \
        }                                                                     \
        __builtin_amdgcn_s_setprio(0);                                        \
        /* ---- p3: B-k1 n2,n3 ---- */                                        \
        __builtin_amdgcn_s_barrier();                                         \
        bfr[2] = *(const bf16x8*)(b1_ + 1024);                                \
        bfr[3] = *(const bf16x8*)(b1_ + 1536);                                \
        if (DO3) STAGE((T) + 2, 2, slB0);   /* slot of B-k0, freed at p1 */   \
        __builtin_amdgcn_s_setprio(1);                                        \
        _Pragma("unroll")                                                     \
        for (int m = 0; m < 8; ++m) {                                         \
            MF(acc[m][2], af[m], bfr[2]);                                     \
            MF(acc[m][3], af[m], bfr[3]);                                     \
        }                                                                     \
        __builtin_amdgcn_s_setprio(0);                                        \
    }                                                                         \
    s4 += 4; if (s4 >= NSLOT) s4 -= NSLOT;                                    \
} while (0)

    #pragma unroll 1
    for (int T = 0; T < 14; ++T)
        TILE_BODY(T, "10", "10", true, true, true, true);
    TILE_BODY(14, "10", "8", true, false, false, false);   // stages half 63
    TILE_BODY(15, "4",  "0", false, false, false, false);  // drain (loads 6+ phases old)

#undef TILE_BODY
#undef STAGE
#undef GLL
#undef MF

    // ---- epilogue: C/D layout col = lane&15, row = quad*4 + reg ----
    float bv[4];
    #pragma unroll
    for (int nt = 0; nt < 4; ++nt)
        bv[nt] = bias[bn * TN + wn + nt * 16 + l16];

    float* Cbase = C + (size_t)(bm * TM + wm) * N + bn * TN + wn;
    #pragma unroll
    for (int m = 0; m < 8; ++m) {
        #pragma unroll
        for (int r = 0; r < 4; ++r) {
            float* crowp = Cbase + (size_t)(m * 16 + quad * 4 + r) * N;
            #pragma unroll
            for (int nt = 0; nt < 4; ++nt)
                crowp[nt * 16 + l16] = acc[m][nt][r] + bv[nt];
        }
    }
}

// ---------------------------------------------------------------------------
extern "C" void kernel_launch(void* const* d_in, const int* in_sizes, int n_in,
                              void* d_out, int out_size, void* d_ws, size_t ws_size,
                              hipStream_t stream) {
    const float* x      = (const float*)d_in[0];   // [16,512,1024]
    const float* weight = (const float*)d_in[1];   // [4096,1024]
    const float* alphas = (const float*)d_in[2];   // [5]
    const float* bias   = (const float*)d_in[3];   // [4096]
    float* out = (float*)d_out;                    // [16,512,4096] f32

    // workspace: Wb (bf16, 8 MB) | Xb (bf16, 16 MB)
    unsigned short* Wb = (unsigned short*)d_ws;
    unsigned short* Xb = (unsigned short*)((char*)d_ws + (size_t)OUT_F * IN_F * 2);

    build_w_kernel<<<(OUT_F / 16) * (IN_F / 256), 256, 0, stream>>>(weight, alphas, Wb);
    cvt_x_kernel<<<(M_DIM * K_DIM / 8) / 256, 256, 0, stream>>>(x, (uint4*)Xb);

    const int grid = (M_DIM / TM) * (N_DIM / TN);   // 32*16 = 512 blocks
    gemm_bt_kernel<<<grid, 512, 0, stream>>>((const bf16*)Xb, (const bf16*)Wb, bias, out);
}